// Round 7
// baseline (168.698 us; speedup 1.0000x reference)
//
#include <hip/hip_runtime.h>
#include <hip/hip_fp16.h>

#define D 128
#define TWO_D 256

typedef _Float16 half2v __attribute__((ext_vector_type(2)));
typedef _Float16 half8v __attribute__((ext_vector_type(8)));
typedef float floatx4 __attribute__((ext_vector_type(4)));

__device__ inline unsigned int pkrtz(float a, float b) {
    return __builtin_bit_cast(unsigned int, __builtin_amdgcn_cvt_pkrtz(a, b));
}

// AB[n][o] = fp8_e4m3( sum_k x[n][k]*W1eff[o][k] + b1eff[o] ), o in [0,256).
// W1eff[o][k] = (o<128) ? W1[o][k] : W1[o-128][128+k]  (concat-GEMM factorization).
// 64 nodes/block, 4 sub-tiles of 16; B-frags built from W1 fp32 directly;
// x pipelined through regs+LDS; epilogue f32->LDS->fp8 repack for coalesced stores.
__global__ __launch_bounds__(256) void gemm_nodes(
        const float* __restrict__ x, const float* __restrict__ W1,
        const float* __restrict__ b1,
        unsigned char* __restrict__ AB, float* __restrict__ out0, int nNodes) {
    const int tid  = threadIdx.x;
    const int wave = tid >> 6, lane = tid & 63;
    const int quad = lane >> 4, l16 = lane & 15;
    const int nb0  = blockIdx.x * 64;

    if (blockIdx.x == 0 && tid == 0) *out0 = 0.f;   // replaces hipMemsetAsync

    // B-operand frags in VGPRs: o = 64*wave + 16t + l16 (B layout n=lane&15),
    // k = 32ks + 8*quad + j. Converted fp32->fp16 at load.
    half8v Bf[4][4];
    float bias[4];
#pragma unroll
    for (int t = 0; t < 4; ++t) {
        const int o = wave * 64 + t * 16 + l16;
        bias[t] = (o < D) ? b1[o] : 0.f;
        const float* wrow = (o < D) ? (W1 + (size_t)o * TWO_D)
                                    : (W1 + (size_t)(o - D) * TWO_D + D);
#pragma unroll
        for (int ks = 0; ks < 4; ++ks) {
            const float* wp = wrow + ks * 32 + quad * 8;
            floatx4 w0 = *(const floatx4*)wp;
            floatx4 w1v = *(const floatx4*)(wp + 4);
            uint4 pk;
            pk.x = pkrtz(w0[0], w0[1]);  pk.y = pkrtz(w0[2], w0[3]);
            pk.z = pkrtz(w1v[0], w1v[1]); pk.w = pkrtz(w1v[2], w1v[3]);
            Bf[t][ks] = __builtin_bit_cast(half8v, pk);
        }
    }

    __shared__ __align__(16) unsigned short xs[16][136];  // x tile fp16, 4.25 KB
    __shared__ __align__(16) float ct[16][260];           // C repack tile f32, 16.6 KB

    const int srow = tid >> 4;   // 0..15
    const int sc8  = tid & 15;   // 0..15

    // prefetch sub 0
    floatx4 v0, v1;
    {
        const int node = nb0 + srow;
        const int nc = node < nNodes ? node : nNodes - 1;
        const float* xp = x + (size_t)nc * D + sc8 * 8;
        v0 = *(const floatx4*)xp;
        v1 = *(const floatx4*)(xp + 4);
    }

    for (int sub = 0; sub < 4; ++sub) {
        __syncthreads();   // prev sub's xs/ct readers done
        uint4 pk;
        pk.x = pkrtz(v0[0], v0[1]);  pk.y = pkrtz(v0[2], v0[3]);
        pk.z = pkrtz(v1[0], v1[1]);  pk.w = pkrtz(v1[2], v1[3]);
        *(uint4*)&xs[srow][sc8 * 8] = pk;
        __syncthreads();   // xs ready

        if (sub < 3) {     // prefetch next sub during MFMA
            const int node = nb0 + (sub + 1) * 16 + srow;
            const int nc = node < nNodes ? node : nNodes - 1;
            const float* xp = x + (size_t)nc * D + sc8 * 8;
            v0 = *(const floatx4*)xp;
            v1 = *(const floatx4*)(xp + 4);
        }

        // A-frags: m = lane&15 (node), k = quad*8 + j + 32*ks
        half8v Af[4];
#pragma unroll
        for (int ks = 0; ks < 4; ++ks)
            Af[ks] = *(const half8v*)&xs[l16][ks * 32 + quad * 8];

        floatx4 acc[4];
#pragma unroll
        for (int t = 0; t < 4; ++t) acc[t] = (floatx4){0.f, 0.f, 0.f, 0.f};
#pragma unroll
        for (int ks = 0; ks < 4; ++ks)
#pragma unroll
            for (int t = 0; t < 4; ++t)
                acc[t] = __builtin_amdgcn_mfma_f32_16x16x32_f16(Af[ks], Bf[t][ks], acc[t], 0, 0, 0);

        // C/D: col(o) = lane&15; row(node-local) = quad*4 + r. Stage f32 in LDS.
#pragma unroll
        for (int t = 0; t < 4; ++t) {
            const int o = wave * 64 + t * 16 + l16;
#pragma unroll
            for (int r = 0; r < 4; ++r)
                ct[quad * 4 + r][o] = acc[t][r] + bias[t];
        }
        __syncthreads();   // ct ready

        const int nrow = nb0 + sub * 16 + srow;
        if (nrow < nNodes) {
            floatx4 f0 = *(const floatx4*)&ct[srow][sc8 * 16];
            floatx4 f1 = *(const floatx4*)&ct[srow][sc8 * 16 + 4];
            floatx4 f2 = *(const floatx4*)&ct[srow][sc8 * 16 + 8];
            floatx4 f3 = *(const floatx4*)&ct[srow][sc8 * 16 + 12];
            uint4 o8;
            int d;
            d = __builtin_amdgcn_cvt_pk_fp8_f32(f0[0], f0[1], 0, false);
            d = __builtin_amdgcn_cvt_pk_fp8_f32(f0[2], f0[3], d, true);
            o8.x = (unsigned int)d;
            d = __builtin_amdgcn_cvt_pk_fp8_f32(f1[0], f1[1], 0, false);
            d = __builtin_amdgcn_cvt_pk_fp8_f32(f1[2], f1[3], d, true);
            o8.y = (unsigned int)d;
            d = __builtin_amdgcn_cvt_pk_fp8_f32(f2[0], f2[1], 0, false);
            d = __builtin_amdgcn_cvt_pk_fp8_f32(f2[2], f2[3], d, true);
            o8.z = (unsigned int)d;
            d = __builtin_amdgcn_cvt_pk_fp8_f32(f3[0], f3[1], 0, false);
            d = __builtin_amdgcn_cvt_pk_fp8_f32(f3[2], f3[3], d, true);
            o8.w = (unsigned int)d;
            *(uint4*)(AB + (size_t)nrow * TWO_D + sc8 * 16) = o8;  // 16 lanes = 256 B
        }
    }
}

// relu(a+b) dot w2 for 4 fp8 elements packed in dwords wa/wb; w2 as 2 f16-pairs.
__device__ inline float dot4_fp8(unsigned int wa, unsigned int wb,
                                 unsigned int w2lo, unsigned int w2hi, float z) {
#if __has_builtin(__builtin_amdgcn_cvt_pk_f16_fp8)
    half2v a01 = __builtin_bit_cast(half2v, __builtin_amdgcn_cvt_pk_f16_fp8((short)(wa & 0xffffu)));
    half2v a23 = __builtin_bit_cast(half2v, __builtin_amdgcn_cvt_pk_f16_fp8((short)(wa >> 16)));
    half2v b01 = __builtin_bit_cast(half2v, __builtin_amdgcn_cvt_pk_f16_fp8((short)(wb & 0xffffu)));
    half2v b23 = __builtin_bit_cast(half2v, __builtin_amdgcn_cvt_pk_f16_fp8((short)(wb >> 16)));
    half2v zero = {(_Float16)0, (_Float16)0};
    half2v s01 = __builtin_elementwise_max(a01 + b01, zero);
    half2v s23 = __builtin_elementwise_max(a23 + b23, zero);
    z = __builtin_amdgcn_fdot2(s01, __builtin_bit_cast(half2v, w2lo), z, false);
    z = __builtin_amdgcn_fdot2(s23, __builtin_bit_cast(half2v, w2hi), z, false);
#else
    auto a01 = __builtin_amdgcn_cvt_pk_f32_fp8(wa, false);
    auto a23 = __builtin_amdgcn_cvt_pk_f32_fp8(wa, true);
    auto b01 = __builtin_amdgcn_cvt_pk_f32_fp8(wb, false);
    auto b23 = __builtin_amdgcn_cvt_pk_f32_fp8(wb, true);
    half2v wlo = __builtin_bit_cast(half2v, w2lo);
    half2v whi = __builtin_bit_cast(half2v, w2hi);
    float s0 = fmaxf(a01[0] + b01[0], 0.f), s1 = fmaxf(a01[1] + b01[1], 0.f);
    float s2 = fmaxf(a23[0] + b23[0], 0.f), s3 = fmaxf(a23[1] + b23[1], 0.f);
    z = fmaf(s0, (float)wlo[0], z); z = fmaf(s1, (float)wlo[1], z);
    z = fmaf(s2, (float)whi[0], z); z = fmaf(s3, (float)whi[1], z);
#endif
    return z;
}

__device__ inline float dot16(const uint4& a4, const uint4& b4,
                              const uint4& w2a, const uint4& w2b) {
    float z = 0.f;
    z = dot4_fp8(a4.x, b4.x, w2a.x, w2a.y, z);
    z = dot4_fp8(a4.y, b4.y, w2a.z, w2a.w, z);
    z = dot4_fp8(a4.z, b4.z, w2b.x, w2b.y, z);
    z = dot4_fp8(a4.w, b4.w, w2b.z, w2b.w, z);
    return z;
}

__device__ inline float red8(float z) {
    z += __shfl_xor(z, 4, 8);
    z += __shfl_xor(z, 2, 8);
    z += __shfl_xor(z, 1, 8);
    return z;
}

__device__ inline float bce(float z, float y) {
    const float t = __expf(-fabsf(z));
    return fmaxf(z, 0.f) - z * y + __logf(1.f + t);
}

// 8 lanes per group, 8 CONSECUTIVE edges per group (E = 600000 = 75000*8).
// Indices + labels for the whole chunk load in ONE coalesced wave instruction
// each; per-edge u/v/label come from register shuffles (no memory latency in
// the chain). 16 gathers per group are all independent, software-pipelined 4
// edges deep -> the only serialized latency turns are idx-batch + first gather.
__global__ __launch_bounds__(256, 8) void edge_loss(
        const unsigned char* __restrict__ AB,
        const int* __restrict__ pairs,
        const float* __restrict__ labels,
        const float* __restrict__ W2,
        const float* __restrict__ b2,
        float* __restrict__ out, int E, float invE) {
    __shared__ unsigned int w2p[64];   // W2 as 64 packed f16 pairs
    const int tid = threadIdx.x;
    if (tid < 64) {
        float2 w = *(const float2*)(W2 + tid * 2);
        half2v p = { (_Float16)w.x, (_Float16)w.y };
        w2p[tid] = __builtin_bit_cast(unsigned int, p);
    }
    __syncthreads();
    const int l8   = tid & 7;
    const int base = tid & 56;                           // group's base lane in wave
    const uint4 w2a = *(const uint4*)&w2p[l8 * 8];       // pairs for j in [16l8, +8)
    const uint4 w2b = *(const uint4*)&w2p[l8 * 8 + 4];   // pairs for j in [16l8+8, +8)
    const float bb2 = b2[0];

    float acc = 0.f;
    const int group = (blockIdx.x * 256 + tid) >> 3;     // one chunk per group
    const int e0 = group * 8;
    if (e0 < E) {                                        // valid chunks are full
        const int el = e0 + l8;
        const int u   = pairs[el];        // wave: 64 consecutive ints, coalesced
        const int v   = pairs[E + el];
        const float lab = labels[el];

        uint4 A[4], B[4];
#pragma unroll
        for (int k = 0; k < 4; ++k) {     // batch 1: edges 0..3, all independent
            const int uk = __shfl(u, base + k, 64);
            const int vk = __shfl(v, base + k, 64);
            A[k] = *(const uint4*)(AB + (size_t)uk * TWO_D + l8 * 16);
            B[k] = *(const uint4*)(AB + (size_t)vk * TWO_D + D + l8 * 16);
        }
#pragma unroll
        for (int k = 0; k < 4; ++k) {     // compute 0..3 while fetching 4..7
            const int uk = __shfl(u, base + 4 + k, 64);
            const int vk = __shfl(v, base + 4 + k, 64);
            uint4 A2 = *(const uint4*)(AB + (size_t)uk * TWO_D + l8 * 16);
            uint4 B2 = *(const uint4*)(AB + (size_t)vk * TWO_D + D + l8 * 16);
            float z = red8(dot16(A[k], B[k], w2a, w2b)) + bb2;
            const float labk = __shfl(lab, base + k, 64);
            if (l8 == 0) acc += bce(z, labk);
            A[k] = A2; B[k] = B2;
        }
#pragma unroll
        for (int k = 0; k < 4; ++k) {     // compute 4..7
            float z = red8(dot16(A[k], B[k], w2a, w2b)) + bb2;
            const float labk = __shfl(lab, base + 4 + k, 64);
            if (l8 == 0) acc += bce(z, labk);
        }
    }

    // wave butterfly -> LDS -> one atomic per block
#pragma unroll
    for (int m = 32; m >= 1; m >>= 1) acc += __shfl_xor(acc, m, 64);
    __shared__ float red[4];
    if ((tid & 63) == 0) red[tid >> 6] = acc;
    __syncthreads();
    if (tid == 0)
        atomicAdd(out, (red[0] + red[1] + red[2] + red[3]) * invE);
}

extern "C" void kernel_launch(void* const* d_in, const int* in_sizes, int n_in,
                              void* d_out, int out_size, void* d_ws, size_t ws_size,
                              hipStream_t stream) {
    const float* x      = (const float*)d_in[0];
    const float* W1     = (const float*)d_in[1];
    const float* b1     = (const float*)d_in[2];
    const float* W2     = (const float*)d_in[3];
    const float* b2     = (const float*)d_in[4];
    const float* labels = (const float*)d_in[5];
    const int*   pairs  = (const int*)d_in[6];

    const int nNodes = in_sizes[0] / D;   // 50000
    const int E      = in_sizes[5];       // 600000

    unsigned char* AB = (unsigned char*)d_ws;   // nNodes*256 fp8 bytes (12.8 MB)

    gemm_nodes<<<(nNodes + 63) / 64, 256, 0, stream>>>(x, W1, b1, AB,
                                                        (float*)d_out, nNodes);
    const int nGroups = (E + 7) / 8;                    // 75000
    const int nBlocks = (nGroups + 31) / 32;            // 2344 (32 groups/block)
    edge_loss<<<nBlocks, 256, 0, stream>>>(AB, pairs, labels, W2, b2,
                                           (float*)d_out, E, 1.0f / (float)E);
}

// Round 8
// 129.460 us; speedup vs baseline: 1.3031x; 1.3031x over previous
//
#include <hip/hip_runtime.h>
#include <hip/hip_fp16.h>

#define D 128
#define TWO_D 256

typedef _Float16 half2v __attribute__((ext_vector_type(2)));
typedef _Float16 half8v __attribute__((ext_vector_type(8)));
typedef float floatx4 __attribute__((ext_vector_type(4)));

__device__ inline unsigned int pkrtz(float a, float b) {
    return __builtin_bit_cast(unsigned int, __builtin_amdgcn_cvt_pkrtz(a, b));
}

// Build Wt in MFMA B-fragment order so gemm's prologue loads are coalesced.
// Fragment element (w,t,ks,lane) = W1eff[o][k], o = 64w+16t+(lane&15),
// k = 32ks + 8*(lane>>4) + j, j=0..7 (8 fp16 = 16 B per lane).
// Wtf[(((w*4+t)*4+ks)*64 + lane)*8 + j]
__global__ void build_wtf(const float* __restrict__ W1,
                          unsigned short* __restrict__ Wtf) {
    const int id = blockIdx.x * 256 + threadIdx.x;   // 4096 total
    const int lane = id & 63, ks = (id >> 6) & 3, t = (id >> 8) & 3, w = id >> 10;
    const int quad = lane >> 4, l16 = lane & 15;
    const int o = w * 64 + t * 16 + l16;
    const float* wrow = (o < D) ? (W1 + (size_t)o * TWO_D)
                                : (W1 + (size_t)(o - D) * TWO_D + D);
    const float* wp = wrow + ks * 32 + quad * 8;
    floatx4 w0 = *(const floatx4*)wp;
    floatx4 w1v = *(const floatx4*)(wp + 4);
    uint4 pk;
    pk.x = pkrtz(w0[0], w0[1]);  pk.y = pkrtz(w0[2], w0[3]);
    pk.z = pkrtz(w1v[0], w1v[1]); pk.w = pkrtz(w1v[2], w1v[3]);
    *(uint4*)(Wtf + (size_t)id * 8) = pk;
}

// AB[n][o] = fp8_e4m3( sum_k x[n][k]*W1eff[o][k] + b1eff[o] ), o in [0,256).
// 64 nodes/block, 4 sub-tiles of 16; Bf loaded COALESCED from frag-ordered Wtf;
// x pipelined through regs+LDS; epilogue f32->LDS->fp8 repack, coalesced stores.
__global__ __launch_bounds__(256) void gemm_nodes(
        const float* __restrict__ x, const unsigned short* __restrict__ Wtf,
        const float* __restrict__ b1,
        unsigned char* __restrict__ AB, float* __restrict__ out0, int nNodes) {
    const int tid  = threadIdx.x;
    const int wave = tid >> 6, lane = tid & 63;
    const int quad = lane >> 4, l16 = lane & 15;
    const int nb0  = blockIdx.x * 64;

    if (blockIdx.x == 0 && tid == 0) *out0 = 0.f;   // replaces hipMemsetAsync

    // B-operand frags: coalesced 16 B/lane loads from fragment-ordered Wtf.
    half8v Bf[4][4];
    float bias[4];
#pragma unroll
    for (int t = 0; t < 4; ++t) {
        const int o = wave * 64 + t * 16 + l16;
        bias[t] = (o < D) ? b1[o] : 0.f;
#pragma unroll
        for (int ks = 0; ks < 4; ++ks)
            Bf[t][ks] = *(const half8v*)(Wtf +
                ((size_t)(((wave * 4 + t) * 4 + ks) * 64) + lane) * 8);
    }

    __shared__ __align__(16) unsigned short xs[16][136];  // x tile fp16, 4.25 KB
    __shared__ __align__(16) float ct[16][260];           // C repack tile f32, 16.6 KB

    const int srow = tid >> 4;   // 0..15
    const int sc8  = tid & 15;   // 0..15

    // prefetch sub 0
    floatx4 v0, v1;
    {
        const int node = nb0 + srow;
        const int nc = node < nNodes ? node : nNodes - 1;
        const float* xp = x + (size_t)nc * D + sc8 * 8;
        v0 = *(const floatx4*)xp;
        v1 = *(const floatx4*)(xp + 4);
    }

    for (int sub = 0; sub < 4; ++sub) {
        __syncthreads();   // prev sub's xs/ct readers done
        uint4 pk;
        pk.x = pkrtz(v0[0], v0[1]);  pk.y = pkrtz(v0[2], v0[3]);
        pk.z = pkrtz(v1[0], v1[1]);  pk.w = pkrtz(v1[2], v1[3]);
        *(uint4*)&xs[srow][sc8 * 8] = pk;
        __syncthreads();   // xs ready

        if (sub < 3) {     // prefetch next sub during MFMA
            const int node = nb0 + (sub + 1) * 16 + srow;
            const int nc = node < nNodes ? node : nNodes - 1;
            const float* xp = x + (size_t)nc * D + sc8 * 8;
            v0 = *(const floatx4*)xp;
            v1 = *(const floatx4*)(xp + 4);
        }

        // A-frags: m = lane&15 (node), k = quad*8 + j + 32*ks
        half8v Af[4];
#pragma unroll
        for (int ks = 0; ks < 4; ++ks)
            Af[ks] = *(const half8v*)&xs[l16][ks * 32 + quad * 8];

        floatx4 acc[4];
#pragma unroll
        for (int t = 0; t < 4; ++t) acc[t] = (floatx4){0.f, 0.f, 0.f, 0.f};
#pragma unroll
        for (int ks = 0; ks < 4; ++ks)
#pragma unroll
            for (int t = 0; t < 4; ++t)
                acc[t] = __builtin_amdgcn_mfma_f32_16x16x32_f16(Af[ks], Bf[t][ks], acc[t], 0, 0, 0);

        // C/D: col(o) = lane&15; row(node-local) = quad*4 + r. Stage f32 in LDS.
#pragma unroll
        for (int t = 0; t < 4; ++t) {
            const int o = wave * 64 + t * 16 + l16;
#pragma unroll
            for (int r = 0; r < 4; ++r)
                ct[quad * 4 + r][o] = acc[t][r] + bias[t];
        }
        __syncthreads();   // ct ready

        const int nrow = nb0 + sub * 16 + srow;
        if (nrow < nNodes) {
            floatx4 f0 = *(const floatx4*)&ct[srow][sc8 * 16];
            floatx4 f1 = *(const floatx4*)&ct[srow][sc8 * 16 + 4];
            floatx4 f2 = *(const floatx4*)&ct[srow][sc8 * 16 + 8];
            floatx4 f3 = *(const floatx4*)&ct[srow][sc8 * 16 + 12];
            uint4 o8;
            int d;
            d = __builtin_amdgcn_cvt_pk_fp8_f32(f0[0], f0[1], 0, false);
            d = __builtin_amdgcn_cvt_pk_fp8_f32(f0[2], f0[3], d, true);
            o8.x = (unsigned int)d;
            d = __builtin_amdgcn_cvt_pk_fp8_f32(f1[0], f1[1], 0, false);
            d = __builtin_amdgcn_cvt_pk_fp8_f32(f1[2], f1[3], d, true);
            o8.y = (unsigned int)d;
            d = __builtin_amdgcn_cvt_pk_fp8_f32(f2[0], f2[1], 0, false);
            d = __builtin_amdgcn_cvt_pk_fp8_f32(f2[2], f2[3], d, true);
            o8.z = (unsigned int)d;
            d = __builtin_amdgcn_cvt_pk_fp8_f32(f3[0], f3[1], 0, false);
            d = __builtin_amdgcn_cvt_pk_fp8_f32(f3[2], f3[3], d, true);
            o8.w = (unsigned int)d;
            *(uint4*)(AB + (size_t)nrow * TWO_D + sc8 * 16) = o8;  // 16 lanes = 256 B
        }
    }
}

// relu(a+b) dot w2 for 4 fp8 elements packed in dwords wa/wb; w2 as 2 f16-pairs.
__device__ inline float dot4_fp8(unsigned int wa, unsigned int wb,
                                 unsigned int w2lo, unsigned int w2hi, float z) {
#if __has_builtin(__builtin_amdgcn_cvt_pk_f16_fp8)
    half2v a01 = __builtin_bit_cast(half2v, __builtin_amdgcn_cvt_pk_f16_fp8((short)(wa & 0xffffu)));
    half2v a23 = __builtin_bit_cast(half2v, __builtin_amdgcn_cvt_pk_f16_fp8((short)(wa >> 16)));
    half2v b01 = __builtin_bit_cast(half2v, __builtin_amdgcn_cvt_pk_f16_fp8((short)(wb & 0xffffu)));
    half2v b23 = __builtin_bit_cast(half2v, __builtin_amdgcn_cvt_pk_f16_fp8((short)(wb >> 16)));
    half2v zero = {(_Float16)0, (_Float16)0};
    half2v s01 = __builtin_elementwise_max(a01 + b01, zero);
    half2v s23 = __builtin_elementwise_max(a23 + b23, zero);
    z = __builtin_amdgcn_fdot2(s01, __builtin_bit_cast(half2v, w2lo), z, false);
    z = __builtin_amdgcn_fdot2(s23, __builtin_bit_cast(half2v, w2hi), z, false);
#else
    auto a01 = __builtin_amdgcn_cvt_pk_f32_fp8(wa, false);
    auto a23 = __builtin_amdgcn_cvt_pk_f32_fp8(wa, true);
    auto b01 = __builtin_amdgcn_cvt_pk_f32_fp8(wb, false);
    auto b23 = __builtin_amdgcn_cvt_pk_f32_fp8(wb, true);
    half2v wlo = __builtin_bit_cast(half2v, w2lo);
    half2v whi = __builtin_bit_cast(half2v, w2hi);
    float s0 = fmaxf(a01[0] + b01[0], 0.f), s1 = fmaxf(a01[1] + b01[1], 0.f);
    float s2 = fmaxf(a23[0] + b23[0], 0.f), s3 = fmaxf(a23[1] + b23[1], 0.f);
    z = fmaf(s0, (float)wlo[0], z); z = fmaf(s1, (float)wlo[1], z);
    z = fmaf(s2, (float)whi[0], z); z = fmaf(s3, (float)whi[1], z);
#endif
    return z;
}

__device__ inline float dot16(const uint4& a4, const uint4& b4,
                              const uint4& w2a, const uint4& w2b) {
    float z = 0.f;
    z = dot4_fp8(a4.x, b4.x, w2a.x, w2a.y, z);
    z = dot4_fp8(a4.y, b4.y, w2a.z, w2a.w, z);
    z = dot4_fp8(a4.z, b4.z, w2b.x, w2b.y, z);
    z = dot4_fp8(a4.w, b4.w, w2b.z, w2b.w, z);
    return z;
}

__device__ inline float red8(float z) {
    z += __shfl_xor(z, 4, 8);
    z += __shfl_xor(z, 2, 8);
    z += __shfl_xor(z, 1, 8);
    return z;
}

__device__ inline float bce(float z, float y) {
    const float t = __expf(-fabsf(z));
    return fmaxf(z, 0.f) - z * y + __logf(1.f + t);
}

// 8 lanes per group, 8 consecutive edges per group. Indices/labels load in one
// coalesced wave instruction; u/v broadcast via register shuffles. ALL 16
// independent 128-B gathers issued before any compute (R7 retry WITHOUT the
// VGPR cap that spilled them to scratch: WRITE_SIZE 42 MB smoking gun).
__global__ __launch_bounds__(256) void edge_loss(
        const unsigned char* __restrict__ AB,
        const int* __restrict__ pairs,
        const float* __restrict__ labels,
        const float* __restrict__ W2,
        const float* __restrict__ b2,
        float* __restrict__ out, int E, float invE) {
    __shared__ unsigned int w2p[64];   // W2 as 64 packed f16 pairs
    const int tid = threadIdx.x;
    if (tid < 64) {
        float2 w = *(const float2*)(W2 + tid * 2);
        half2v p = { (_Float16)w.x, (_Float16)w.y };
        w2p[tid] = __builtin_bit_cast(unsigned int, p);
    }
    __syncthreads();
    const int l8   = tid & 7;
    const int base = tid & 56;                           // group's base lane in wave
    const uint4 w2a = *(const uint4*)&w2p[l8 * 8];       // pairs for j in [16l8, +8)
    const uint4 w2b = *(const uint4*)&w2p[l8 * 8 + 4];   // pairs for j in [16l8+8, +8)
    const float bb2 = b2[0];

    float acc = 0.f;
    const int group = (blockIdx.x * 256 + tid) >> 3;     // one 8-edge chunk per group
    const int e0 = group * 8;
    if (e0 < E) {                                        // E % 8 == 0: full chunks
        const int el = e0 + l8;
        const int u    = pairs[el];       // wave: 64 consecutive ints, coalesced
        const int v    = pairs[E + el];
        const float lab = labels[el];

        uint4 A[8], B[8];
#pragma unroll
        for (int k = 0; k < 8; ++k) {     // all 16 gathers independent, in flight
            const int uk = __shfl(u, base + k, 64);
            const int vk = __shfl(v, base + k, 64);
            A[k] = *(const uint4*)(AB + (size_t)uk * TWO_D + l8 * 16);
            B[k] = *(const uint4*)(AB + (size_t)vk * TWO_D + D + l8 * 16);
        }
#pragma unroll
        for (int k = 0; k < 8; ++k) {
            float z = red8(dot16(A[k], B[k], w2a, w2b)) + bb2;
            const float labk = __shfl(lab, base + k, 64);
            if (l8 == 0) acc += bce(z, labk);
        }
    }

    // wave butterfly -> LDS -> one atomic per block
#pragma unroll
    for (int m = 32; m >= 1; m >>= 1) acc += __shfl_xor(acc, m, 64);
    __shared__ float red[4];
    if ((tid & 63) == 0) red[tid >> 6] = acc;
    __syncthreads();
    if (tid == 0)
        atomicAdd(out, (red[0] + red[1] + red[2] + red[3]) * invE);
}

extern "C" void kernel_launch(void* const* d_in, const int* in_sizes, int n_in,
                              void* d_out, int out_size, void* d_ws, size_t ws_size,
                              hipStream_t stream) {
    const float* x      = (const float*)d_in[0];
    const float* W1     = (const float*)d_in[1];
    const float* b1     = (const float*)d_in[2];
    const float* W2     = (const float*)d_in[3];
    const float* b2     = (const float*)d_in[4];
    const float* labels = (const float*)d_in[5];
    const int*   pairs  = (const int*)d_in[6];

    const int nNodes = in_sizes[0] / D;   // 50000
    const int E      = in_sizes[5];       // 600000

    unsigned char*  AB  = (unsigned char*)d_ws;                       // 12.8 MB fp8
    unsigned short* Wtf = (unsigned short*)((char*)d_ws + 13000704);  // 64 KiB frag-order

    build_wtf<<<16, 256, 0, stream>>>(W1, Wtf);
    gemm_nodes<<<(nNodes + 63) / 64, 256, 0, stream>>>(x, Wtf, b1, AB,
                                                        (float*)d_out, nNodes);
    const int nGroups = (E + 7) / 8;                    // 75000
    const int nBlocks = (nGroups + 31) / 32;            // 2344 (32 groups/block)
    edge_loss<<<nBlocks, 256, 0, stream>>>(AB, pairs, labels, W2, b2,
                                           (float*)d_out, E, 1.0f / (float)E);
}

// Round 9
// 125.763 us; speedup vs baseline: 1.3414x; 1.0294x over previous
//
#include <hip/hip_runtime.h>
#include <hip/hip_fp16.h>

#define D 128
#define TWO_D 256

typedef _Float16 half2v __attribute__((ext_vector_type(2)));
typedef _Float16 half8v __attribute__((ext_vector_type(8)));
typedef float floatx4 __attribute__((ext_vector_type(4)));

__device__ inline unsigned int pkrtz(float a, float b) {
    return __builtin_bit_cast(unsigned int, __builtin_amdgcn_cvt_pkrtz(a, b));
}

// Build Wt in MFMA B-fragment order so gemm's prologue loads are coalesced.
// Fragment element (w,t,ks,lane) = W1eff[o][k], o = 64w+16t+(lane&15),
// k = 32ks + 8*(lane>>4) + j, j=0..7 (8 fp16 = 16 B per lane).
__global__ void build_wtf(const float* __restrict__ W1,
                          unsigned short* __restrict__ Wtf) {
    const int id = blockIdx.x * 256 + threadIdx.x;   // 4096 total
    const int lane = id & 63, ks = (id >> 6) & 3, t = (id >> 8) & 3, w = id >> 10;
    const int quad = lane >> 4, l16 = lane & 15;
    const int o = w * 64 + t * 16 + l16;
    const float* wrow = (o < D) ? (W1 + (size_t)o * TWO_D)
                                : (W1 + (size_t)(o - D) * TWO_D + D);
    const float* wp = wrow + ks * 32 + quad * 8;
    floatx4 w0 = *(const floatx4*)wp;
    floatx4 w1v = *(const floatx4*)(wp + 4);
    uint4 pk;
    pk.x = pkrtz(w0[0], w0[1]);  pk.y = pkrtz(w0[2], w0[3]);
    pk.z = pkrtz(w1v[0], w1v[1]); pk.w = pkrtz(w1v[2], w1v[3]);
    *(uint4*)(Wtf + (size_t)id * 8) = pk;
}

// AB[n][o] = fp8_e4m3( sum_k x[n][k]*W1eff[o][k] + b1eff[o] ), o in [0,256).
// v4: ALL 64 node-rows staged upfront (bulk coalesced, 17.4 KB), then per sub:
// MFMA -> ct write -> ONE barrier -> coalesced fp8 store, with ping-pong ct
// buffers. 5 barriers/block instead of 12 (R8) -> no per-sub vmcnt(0) drains.
__global__ __launch_bounds__(256) void gemm_nodes(
        const float* __restrict__ x, const unsigned short* __restrict__ Wtf,
        const float* __restrict__ b1,
        unsigned char* __restrict__ AB, float* __restrict__ out0, int nNodes) {
    const int tid  = threadIdx.x;
    const int wave = tid >> 6, lane = tid & 63;
    const int quad = lane >> 4, l16 = lane & 15;
    const int nb0  = blockIdx.x * 64;

    if (blockIdx.x == 0 && tid == 0) *out0 = 0.f;   // replaces hipMemsetAsync

    // B-operand frags: coalesced 16 B/lane loads from fragment-ordered Wtf.
    half8v Bf[4][4];
    float bias[4];
#pragma unroll
    for (int t = 0; t < 4; ++t) {
        const int o = wave * 64 + t * 16 + l16;
        bias[t] = (o < D) ? b1[o] : 0.f;
#pragma unroll
        for (int ks = 0; ks < 4; ++ks)
            Bf[t][ks] = *(const half8v*)(Wtf +
                ((size_t)(((wave * 4 + t) * 4 + ks) * 64) + lane) * 8);
    }

    __shared__ __align__(16) unsigned short xs[64][136];   // all 64 rows, 17.4 KB
    __shared__ __align__(16) float ct[2][16][260];         // ping-pong repack, 33.3 KB

    // Phase 1: stage all 64 node-rows fp16 (1024 8-float chunks / 256 threads).
#pragma unroll
    for (int i = 0; i < 4; ++i) {
        const int c = tid + 256 * i;          // 0..1023
        const int row = c >> 4, col8 = c & 15;
        const int node = nb0 + row;
        const int nc = node < nNodes ? node : nNodes - 1;
        const float* xp = x + (size_t)nc * D + col8 * 8;
        floatx4 v0 = *(const floatx4*)xp;
        floatx4 v1 = *(const floatx4*)(xp + 4);
        uint4 pk;
        pk.x = pkrtz(v0[0], v0[1]);  pk.y = pkrtz(v0[2], v0[3]);
        pk.z = pkrtz(v1[0], v1[1]);  pk.w = pkrtz(v1[2], v1[3]);
        *(uint4*)&xs[row][col8 * 8] = pk;
    }
    __syncthreads();   // xs fully staged (sole full-drain barrier)

    const int srow = tid >> 4;   // 0..15 (store-phase row within sub-tile)
    const int sc8  = tid & 15;   // 0..15 (16-byte column block)

    for (int sub = 0; sub < 4; ++sub) {
        // A-frags: m = lane&15 (node within sub-tile), k = quad*8 + j + 32*ks
        half8v Af[4];
#pragma unroll
        for (int ks = 0; ks < 4; ++ks)
            Af[ks] = *(const half8v*)&xs[sub * 16 + l16][ks * 32 + quad * 8];

        floatx4 acc[4];
#pragma unroll
        for (int t = 0; t < 4; ++t) acc[t] = (floatx4){0.f, 0.f, 0.f, 0.f};
#pragma unroll
        for (int ks = 0; ks < 4; ++ks)
#pragma unroll
            for (int t = 0; t < 4; ++t)
                acc[t] = __builtin_amdgcn_mfma_f32_16x16x32_f16(Af[ks], Bf[t][ks], acc[t], 0, 0, 0);

        // C/D: col(o) = lane&15; row(node-local) = quad*4 + r.
        float (*cts)[260] = ct[sub & 1];
#pragma unroll
        for (int t = 0; t < 4; ++t) {
            const int o = wave * 64 + t * 16 + l16;
#pragma unroll
            for (int r = 0; r < 4; ++r)
                cts[quad * 4 + r][o] = acc[t][r] + bias[t];
        }
        __syncthreads();   // ct[sub&1] ready; prior readers of this buffer done
                           // (they read it before the PREVIOUS sync, 2 subs ago)

        const int nrow = nb0 + sub * 16 + srow;
        if (nrow < nNodes) {
            floatx4 f0 = *(const floatx4*)&cts[srow][sc8 * 16];
            floatx4 f1 = *(const floatx4*)&cts[srow][sc8 * 16 + 4];
            floatx4 f2 = *(const floatx4*)&cts[srow][sc8 * 16 + 8];
            floatx4 f3 = *(const floatx4*)&cts[srow][sc8 * 16 + 12];
            uint4 o8;
            int d;
            d = __builtin_amdgcn_cvt_pk_fp8_f32(f0[0], f0[1], 0, false);
            d = __builtin_amdgcn_cvt_pk_fp8_f32(f0[2], f0[3], d, true);
            o8.x = (unsigned int)d;
            d = __builtin_amdgcn_cvt_pk_fp8_f32(f1[0], f1[1], 0, false);
            d = __builtin_amdgcn_cvt_pk_fp8_f32(f1[2], f1[3], d, true);
            o8.y = (unsigned int)d;
            d = __builtin_amdgcn_cvt_pk_fp8_f32(f2[0], f2[1], 0, false);
            d = __builtin_amdgcn_cvt_pk_fp8_f32(f2[2], f2[3], d, true);
            o8.z = (unsigned int)d;
            d = __builtin_amdgcn_cvt_pk_fp8_f32(f3[0], f3[1], 0, false);
            d = __builtin_amdgcn_cvt_pk_fp8_f32(f3[2], f3[3], d, true);
            o8.w = (unsigned int)d;
            *(uint4*)(AB + (size_t)nrow * TWO_D + sc8 * 16) = o8;  // 256 B/16 lanes
        }
    }
}

// relu(a+b) dot w2 for 4 fp8 elements packed in dwords wa/wb; w2 as 2 f16-pairs.
__device__ inline float dot4_fp8(unsigned int wa, unsigned int wb,
                                 unsigned int w2lo, unsigned int w2hi, float z) {
#if __has_builtin(__builtin_amdgcn_cvt_pk_f16_fp8)
    half2v a01 = __builtin_bit_cast(half2v, __builtin_amdgcn_cvt_pk_f16_fp8((short)(wa & 0xffffu)));
    half2v a23 = __builtin_bit_cast(half2v, __builtin_amdgcn_cvt_pk_f16_fp8((short)(wa >> 16)));
    half2v b01 = __builtin_bit_cast(half2v, __builtin_amdgcn_cvt_pk_f16_fp8((short)(wb & 0xffffu)));
    half2v b23 = __builtin_bit_cast(half2v, __builtin_amdgcn_cvt_pk_f16_fp8((short)(wb >> 16)));
    half2v zero = {(_Float16)0, (_Float16)0};
    half2v s01 = __builtin_elementwise_max(a01 + b01, zero);
    half2v s23 = __builtin_elementwise_max(a23 + b23, zero);
    z = __builtin_amdgcn_fdot2(s01, __builtin_bit_cast(half2v, w2lo), z, false);
    z = __builtin_amdgcn_fdot2(s23, __builtin_bit_cast(half2v, w2hi), z, false);
#else
    auto a01 = __builtin_amdgcn_cvt_pk_f32_fp8(wa, false);
    auto a23 = __builtin_amdgcn_cvt_pk_f32_fp8(wa, true);
    auto b01 = __builtin_amdgcn_cvt_pk_f32_fp8(wb, false);
    auto b23 = __builtin_amdgcn_cvt_pk_f32_fp8(wb, true);
    half2v wlo = __builtin_bit_cast(half2v, w2lo);
    half2v whi = __builtin_bit_cast(half2v, w2hi);
    float s0 = fmaxf(a01[0] + b01[0], 0.f), s1 = fmaxf(a01[1] + b01[1], 0.f);
    float s2 = fmaxf(a23[0] + b23[0], 0.f), s3 = fmaxf(a23[1] + b23[1], 0.f);
    z = fmaf(s0, (float)wlo[0], z); z = fmaf(s1, (float)wlo[1], z);
    z = fmaf(s2, (float)whi[0], z); z = fmaf(s3, (float)whi[1], z);
#endif
    return z;
}

__device__ inline float dot16(const uint4& a4, const uint4& b4,
                              const uint4& w2a, const uint4& w2b) {
    float z = 0.f;
    z = dot4_fp8(a4.x, b4.x, w2a.x, w2a.y, z);
    z = dot4_fp8(a4.y, b4.y, w2a.z, w2a.w, z);
    z = dot4_fp8(a4.z, b4.z, w2b.x, w2b.y, z);
    z = dot4_fp8(a4.w, b4.w, w2b.z, w2b.w, z);
    return z;
}

__device__ inline float red8(float z) {
    z += __shfl_xor(z, 4, 8);
    z += __shfl_xor(z, 2, 8);
    z += __shfl_xor(z, 1, 8);
    return z;
}

__device__ inline float bce(float z, float y) {
    const float t = __expf(-fabsf(z));
    return fmaxf(z, 0.f) - z * y + __logf(1.f + t);
}

// 8 lanes per group, 8 consecutive edges per group — byte-identical to R8
// (clean A/B: this round only gemm changed).
__global__ __launch_bounds__(256) void edge_loss(
        const unsigned char* __restrict__ AB,
        const int* __restrict__ pairs,
        const float* __restrict__ labels,
        const float* __restrict__ W2,
        const float* __restrict__ b2,
        float* __restrict__ out, int E, float invE) {
    __shared__ unsigned int w2p[64];   // W2 as 64 packed f16 pairs
    const int tid = threadIdx.x;
    if (tid < 64) {
        float2 w = *(const float2*)(W2 + tid * 2);
        half2v p = { (_Float16)w.x, (_Float16)w.y };
        w2p[tid] = __builtin_bit_cast(unsigned int, p);
    }
    __syncthreads();
    const int l8   = tid & 7;
    const int base = tid & 56;                           // group's base lane in wave
    const uint4 w2a = *(const uint4*)&w2p[l8 * 8];       // pairs for j in [16l8, +8)
    const uint4 w2b = *(const uint4*)&w2p[l8 * 8 + 4];   // pairs for j in [16l8+8, +8)
    const float bb2 = b2[0];

    float acc = 0.f;
    const int group = (blockIdx.x * 256 + tid) >> 3;     // one 8-edge chunk per group
    const int e0 = group * 8;
    if (e0 < E) {                                        // E % 8 == 0: full chunks
        const int el = e0 + l8;
        const int u    = pairs[el];       // wave: 64 consecutive ints, coalesced
        const int v    = pairs[E + el];
        const float lab = labels[el];

        uint4 A[8], B[8];
#pragma unroll
        for (int k = 0; k < 8; ++k) {     // all 16 gathers independent, in flight
            const int uk = __shfl(u, base + k, 64);
            const int vk = __shfl(v, base + k, 64);
            A[k] = *(const uint4*)(AB + (size_t)uk * TWO_D + l8 * 16);
            B[k] = *(const uint4*)(AB + (size_t)vk * TWO_D + D + l8 * 16);
        }
#pragma unroll
        for (int k = 0; k < 8; ++k) {
            float z = red8(dot16(A[k], B[k], w2a, w2b)) + bb2;
            const float labk = __shfl(lab, base + k, 64);
            if (l8 == 0) acc += bce(z, labk);
        }
    }

    // wave butterfly -> LDS -> one atomic per block
#pragma unroll
    for (int m = 32; m >= 1; m >>= 1) acc += __shfl_xor(acc, m, 64);
    __shared__ float red[4];
    if ((tid & 63) == 0) red[tid >> 6] = acc;
    __syncthreads();
    if (tid == 0)
        atomicAdd(out, (red[0] + red[1] + red[2] + red[3]) * invE);
}

extern "C" void kernel_launch(void* const* d_in, const int* in_sizes, int n_in,
                              void* d_out, int out_size, void* d_ws, size_t ws_size,
                              hipStream_t stream) {
    const float* x      = (const float*)d_in[0];
    const float* W1     = (const float*)d_in[1];
    const float* b1     = (const float*)d_in[2];
    const float* W2     = (const float*)d_in[3];
    const float* b2     = (const float*)d_in[4];
    const float* labels = (const float*)d_in[5];
    const int*   pairs  = (const int*)d_in[6];

    const int nNodes = in_sizes[0] / D;   // 50000
    const int E      = in_sizes[5];       // 600000

    unsigned char*  AB  = (unsigned char*)d_ws;                       // 12.8 MB fp8
    unsigned short* Wtf = (unsigned short*)((char*)d_ws + 13000704);  // 64 KiB frag-order

    build_wtf<<<16, 256, 0, stream>>>(W1, Wtf);
    gemm_nodes<<<(nNodes + 63) / 64, 256, 0, stream>>>(x, Wtf, b1, AB,
                                                        (float*)d_out, nNodes);
    const int nGroups = (E + 7) / 8;                    // 75000
    const int nBlocks = (nGroups + 31) / 32;            // 2344 (32 groups/block)
    edge_loss<<<nBlocks, 256, 0, stream>>>(AB, pairs, labels, W2, b2,
                                           (float*)d_out, E, 1.0f / (float)E);
}